// Round 7
// baseline (5800.477 us; speedup 1.0000x reference)
//
#include <hip/hip_runtime.h>
#include <hip/hip_bf16.h>
#include <cstdint>
#include <cstddef>

#define NN 20000
#define HH 128
#define MM 16
#define KK 4000
#define EE 400000

typedef __attribute__((ext_vector_type(4), may_alias)) float f4ma;
typedef __attribute__((ext_vector_type(2), may_alias)) float f2ma;
typedef unsigned __attribute__((may_alias)) u32ma;
typedef float __attribute__((may_alias)) f32ma;

// Wave-local LDS ordering fence (completion wait + scheduler pin).
#define LDS_FENCE() do { \
    asm volatile("s_waitcnt lgkmcnt(0)" ::: "memory"); \
    __builtin_amdgcn_sched_barrier(0); \
  } while (0)

__device__ __forceinline__ float gelu_f(float x) {
  return 0.5f * x * (1.0f + erff(x * 0.70710678118654752440f));
}

__device__ __forceinline__ unsigned short f2bf(float f) {
  union { float f; unsigned u; } v; v.f = f;
  unsigned u = v.u;
  unsigned r = (u + 0x7FFFu + ((u >> 16) & 1u)) >> 16;  // RNE
  return (unsigned short)r;
}
__device__ __forceinline__ float bf2f(unsigned short s) {
  union { unsigned u; float f; } v; v.u = ((unsigned)s) << 16; return v.f;
}
__device__ __forceinline__ void unpack2(unsigned w, float& lo, float& hi) {
  lo = bf2f((unsigned short)(w & 0xFFFFu));
  hi = bf2f((unsigned short)(w >> 16));
}

// ---------------- GCN helper kernels (validated) ----------------

__global__ void zero2_kernel(int* __restrict__ a, int* __restrict__ b, int n) {
  int i = blockIdx.x * 256 + threadIdx.x;
  if (i < n) { a[i] = 0; b[i] = 0; }
}

__global__ void count_kernel(const int* __restrict__ dst, int* __restrict__ cnt, int n) {
  int e = blockIdx.x * 256 + threadIdx.x;
  if (e < n) atomicAdd(&cnt[dst[e]], 1);
}

__global__ void dinv_kernel(const int* __restrict__ cnt, float* __restrict__ dinv, int n) {
  int i = blockIdx.x * 256 + threadIdx.x;
  if (i < n) dinv[i] = rsqrtf((float)(cnt[i] + 1));
}

__global__ void scan_kernel(const int* __restrict__ cnt, int* __restrict__ offs, int n) {
  __shared__ int sh[1024];
  __shared__ int carry_s;
  int tid = threadIdx.x;
  if (tid == 0) carry_s = 0;
  __syncthreads();
  for (int base = 0; base < n; base += 1024) {
    int i = base + tid;
    int v = (i < n) ? cnt[i] : 0;
    sh[tid] = v;
    __syncthreads();
    for (int off = 1; off < 1024; off <<= 1) {
      int t = (tid >= off) ? sh[tid - off] : 0;
      __syncthreads();
      sh[tid] += t;
      __syncthreads();
    }
    int carry = carry_s;
    if (i < n) offs[i] = carry + sh[tid] - v;
    __syncthreads();
    if (tid == 1023) carry_s = carry + sh[1023];
    __syncthreads();
  }
  if (tid == 0) offs[n] = carry_s;
}

__global__ void fillcsr_kernel(const int* __restrict__ esrc, const int* __restrict__ edst,
                               const int* __restrict__ offs, int* __restrict__ cursor,
                               const float* __restrict__ dinv,
                               int* __restrict__ csrc, float* __restrict__ cnorm, int n) {
  int e = blockIdx.x * 256 + threadIdx.x;
  if (e < n) {
    int s = esrc[e], d = edst[e];
    int pos = offs[d] + atomicAdd(&cursor[d], 1);
    csrc[pos] = s;
    cnorm[pos] = dinv[s] * dinv[d];
  }
}

__global__ __launch_bounds__(128) void agg_kernel(const float* __restrict__ X,
    const int* __restrict__ csrc, const float* __restrict__ cnorm,
    const int* __restrict__ offs, const float* __restrict__ dinv,
    const float* __restrict__ bias, int relu, float* __restrict__ Y) {
  int i = blockIdx.x, c = threadIdx.x;
  float di = dinv[i];
  float acc = X[(size_t)i * HH + c] * di * di;
  int s = offs[i], e = offs[i + 1];
  for (int j = s; j < e; ++j) {
    acc += X[(size_t)csrc[j] * HH + c] * cnorm[j];
  }
  acc += bias[c];
  if (relu) acc = fmaxf(acc, 0.f);
  Y[(size_t)i * HH + c] = acc;
}

__global__ __launch_bounds__(128) void gemm128_kernel(const float* __restrict__ X,
    const float* __restrict__ W, float* __restrict__ Y, int nrows) {
  __shared__ float Ws[128 * 129];
  __shared__ float Xs[8 * 128];
  int tid = threadIdx.x;
  for (int idx = tid; idx < 16384; idx += 128) {
    int o = idx >> 7, k = idx & 127;
    Ws[o * 129 + k] = W[idx];
  }
  __syncthreads();
  for (int row0 = blockIdx.x * 8; row0 < nrows; row0 += gridDim.x * 8) {
    int nr = min(8, nrows - row0);
    for (int idx = tid; idx < nr * 128; idx += 128) Xs[idx] = X[(size_t)row0 * 128 + idx];
    __syncthreads();
    float acc[8] = {0, 0, 0, 0, 0, 0, 0, 0};
    for (int k = 0; k < 128; ++k) {
      float w = Ws[tid * 129 + k];
#pragma unroll
      for (int r = 0; r < 8; ++r) acc[r] += w * Xs[r * 128 + k];
    }
    for (int r = 0; r < nr; ++r) Y[(size_t)(row0 + r) * 128 + tid] = acc[r];
    __syncthreads();
  }
}

__global__ void mask_kernel(const int* __restrict__ nodes, float* __restrict__ H, int kn) {
  int idx = blockIdx.x * 256 + threadIdx.x;
  if (idx < kn * HH) {
    int j = idx >> 7, c = idx & 127;
    H[(size_t)nodes[j] * HH + c] = 0.f;
  }
}

__global__ void bcast_kernel(float* __restrict__ out, int total) {
  int idx = blockIdx.x * 256 + threadIdx.x + 128;
  if (idx < total) out[idx] = out[idx & 127];
}

// ---------------- mixer v7: wave-per-node, column-owned means, no scratch ----------------
// Lane (q = lane>>4, h = lane&15) owns output columns cb = q*32+2h, cb+1.
// P1 row load -> P2 write RAW x + per-row (mu,rs) to tile (slack cols 128/129)
// -> P3 column pass: LN1 on the fly, token-MLP, residual in regs, colsum cs
//    (lane-local!), write x_new -> P4 row pass: LN2 -> z2
// -> P5 matmul1 (VALU, bf16 W, broadcast z rows) -> hidden cols
// -> P6 matmul2 + lane-local colsum -> P7 out = (cs + cs_ch)/16.
// No runtime-indexed register arrays anywhere (rule #20).

__global__ __launch_bounds__(512, 2) void mixer7_kernel(
    const float* __restrict__ hbufs,  // [7][NN][HH]
    const float* __restrict__ tn_g, const float* __restrict__ tn_b,
    const float* __restrict__ tok_w1, const float* __restrict__ tok_b1,
    const float* __restrict__ tok_w2, const float* __restrict__ tok_b2,
    const float* __restrict__ cn_g, const float* __restrict__ cn_b,
    const float* __restrict__ ch_w1, const float* __restrict__ ch_b1,
    const float* __restrict__ ch_w2, const float* __restrict__ ch_b2,
    float* __restrict__ out, int total_items) {
  __shared__ __align__(16) unsigned short Wt1[128 * 128];  // 32 KB, [k][o] bf16
  __shared__ __align__(16) unsigned short Wt2[128 * 128];  // 32 KB
  __shared__ __align__(16) float zf[8][16 * 132];          // 67.6 KB per-wave tiles
  __shared__ float tg[128], tbv[128], cg[128], cbv[128], cb1v[128], cb2v[128];
  __shared__ float tw1s[256], tw2s[256], tb1s[16], tb2s[16];

  const int tid = threadIdx.x;

  for (int idx = tid; idx < 16384; idx += 512) {
    int o = idx >> 7, k = idx & 127;
    Wt1[k * 128 + o] = f2bf(ch_w1[idx]);
    Wt2[k * 128 + o] = f2bf(ch_w2[idx]);
  }
  if (tid < 128) {
    tg[tid] = tn_g[tid]; tbv[tid] = tn_b[tid];
    cg[tid] = cn_g[tid]; cbv[tid] = cn_b[tid];
    cb1v[tid] = ch_b1[tid]; cb2v[tid] = ch_b2[tid];
  }
  if (tid < 256) { tw1s[tid] = tok_w1[tid]; tw2s[tid] = tok_w2[tid]; }
  if (tid < 16) { tb1s[tid] = tok_b1[tid]; tb2s[tid] = tok_b2[tid]; }
  __syncthreads();  // only block barrier

  const int wid = tid >> 6;
  const int lane = tid & 63;
  const int q = lane >> 4;
  const int h = lane & 15;
  f32ma* zw = (f32ma*)zf[wid];
  const int cb = q * 32 + 2 * h;

  const int gwave = blockIdx.x * 8 + wid;
  const int wstride = gridDim.x * 8;

  for (int item = gwave; item < total_items; item += wstride) {
    int t, node;
    if (item < 7 * NN) { t = item / NN + 1; node = item % NN; }
    else { t = 0; node = 0; }

    // ---- P1+P2: load row h, LN1 stats, write RAW x + (mu,rs) to tile ----
    {
      float xr[32];
      int src_t = h - (MM - t);
      if (src_t >= 0) {
        const float* hp = hbufs + ((size_t)src_t * NN + node) * HH + q * 32;
#pragma unroll
        for (int j = 0; j < 8; ++j) {
          f4ma v = *(const f4ma*)(hp + 4 * j);
          xr[4 * j] = v.x; xr[4 * j + 1] = v.y; xr[4 * j + 2] = v.z; xr[4 * j + 3] = v.w;
        }
      } else {
#pragma unroll
        for (int j = 0; j < 32; ++j) xr[j] = 0.f;
      }
      float s = 0.f, ss = 0.f;
#pragma unroll
      for (int j = 0; j < 32; ++j) { s += xr[j]; ss += xr[j] * xr[j]; }
      s += __shfl_xor(s, 16); ss += __shfl_xor(ss, 16);
      s += __shfl_xor(s, 32); ss += __shfl_xor(ss, 32);
      float mu = s * (1.f / 128.f);
      float var = fmaxf(ss * (1.f / 128.f) - mu * mu, 0.f);
      float rs = rsqrtf(var + 1e-5f);
#pragma unroll
      for (int m = 0; m < 8; ++m) {
        f4ma w;
        w.x = xr[4 * m]; w.y = xr[4 * m + 1]; w.z = xr[4 * m + 2]; w.w = xr[4 * m + 3];
        *(f4ma*)&zw[h * 132 + q * 32 + 4 * m] = w;
      }
      if (q == 0) {
        zw[h * 132 + 128] = mu;
        zw[h * 132 + 129] = rs;
      }
    }
    LDS_FENCE();   // x + (mu,rs) visible

    // ---- P3: column pass — LN1 on the fly, token-MLP, residual, colsum ----
    float cs0, cs1;
    {
      float xv0[16], xv1[16];
      float z0[16], z1[16];
      const float tg0 = tg[cb], tb0 = tbv[cb], tg1 = tg[cb + 1], tb1 = tbv[cb + 1];
#pragma unroll
      for (int r = 0; r < 16; ++r) {
        f2ma v = *(const f2ma*)&zw[r * 132 + cb];
        float mu = zw[r * 132 + 128];   // uniform addr -> broadcast
        float rs = zw[r * 132 + 129];
        xv0[r] = v.x; xv1[r] = v.y;
        z0[r] = (v.x - mu) * rs * tg0 + tb0;
        z1[r] = (v.y - mu) * rs * tg1 + tb1;
      }
      float a0[16], a1[16];
#pragma unroll
      for (int hd = 0; hd < 16; ++hd) { a0[hd] = tb1s[hd]; a1[hd] = tb1s[hd]; }
#pragma unroll
      for (int r = 0; r < 16; ++r) {
#pragma unroll
        for (int hd = 0; hd < 16; ++hd) {
          float w = tw1s[hd * 16 + r];
          a0[hd] += w * z0[r]; a1[hd] += w * z1[r];
        }
      }
#pragma unroll
      for (int hd = 0; hd < 16; ++hd) { a0[hd] = gelu_f(a0[hd]); a1[hd] = gelu_f(a1[hd]); }
      cs0 = 0.f; cs1 = 0.f;
#pragma unroll
      for (int r = 0; r < 16; ++r) {
        float o0 = tb2s[r], o1 = tb2s[r];
#pragma unroll
        for (int hd = 0; hd < 16; ++hd) {
          float w = tw2s[r * 16 + hd];
          o0 += w * a0[hd]; o1 += w * a1[hd];
        }
        xv0[r] += o0; xv1[r] += o1;          // x_new
        cs0 += xv0[r]; cs1 += xv1[r];        // lane-local token-sum
        f2ma v; v.x = xv0[r]; v.y = xv1[r];
        *(f2ma*)&zw[r * 132 + cb] = v;
      }
    }
    LDS_FENCE();   // x_new visible

    // ---- P4: row pass — LN2 -> z2 ----
    {
      float xr[32];
#pragma unroll
      for (int j = 0; j < 8; ++j) {
        f4ma v = *(const f4ma*)&zw[h * 132 + q * 32 + 4 * j];
        xr[4 * j] = v.x; xr[4 * j + 1] = v.y; xr[4 * j + 2] = v.z; xr[4 * j + 3] = v.w;
      }
      float s = 0.f, ss = 0.f;
#pragma unroll
      for (int j = 0; j < 32; ++j) { s += xr[j]; ss += xr[j] * xr[j]; }
      s += __shfl_xor(s, 16); ss += __shfl_xor(ss, 16);
      s += __shfl_xor(s, 32); ss += __shfl_xor(ss, 32);
      float mu = s * (1.f / 128.f);
      float var = fmaxf(ss * (1.f / 128.f) - mu * mu, 0.f);
      float rs = rsqrtf(var + 1e-5f);
      LDS_FENCE();  // all column reads of x_new done before z2 overwrite
#pragma unroll
      for (int m = 0; m < 8; ++m) {
        f4ma w;
        int c = q * 32 + 4 * m;
        w.x = (xr[4 * m]     - mu) * rs * cg[c]     + cbv[c];
        w.y = (xr[4 * m + 1] - mu) * rs * cg[c + 1] + cbv[c + 1];
        w.z = (xr[4 * m + 2] - mu) * rs * cg[c + 2] + cbv[c + 2];
        w.w = (xr[4 * m + 3] - mu) * rs * cg[c + 3] + cbv[c + 3];
        *(f4ma*)&zw[h * 132 + c] = w;
      }
    }
    LDS_FENCE();   // z2 visible

    // ---- P5: channel matmul1 (f32 VALU): hidden = gelu(z2 @ W1^T + b1) ----
    float h0[16], h1[16];
    {
      float b0 = cb1v[cb], b1 = cb1v[cb + 1];
#pragma unroll
      for (int r = 0; r < 16; ++r) { h0[r] = b0; h1[r] = b1; }
      for (int k = 0; k < 128; k += 4) {
        float w0[4], w1[4];
#pragma unroll
        for (int kk = 0; kk < 4; ++kk) {
          unsigned w = *(const u32ma*)&Wt1[(k + kk) * 128 + cb];
          unpack2(w, w0[kk], w1[kk]);
        }
#pragma unroll
        for (int r = 0; r < 16; ++r) {
          f4ma z4 = *(const f4ma*)&zw[r * 132 + k];   // uniform addr -> broadcast
          h0[r] += z4.x * w0[0] + z4.y * w0[1] + z4.z * w0[2] + z4.w * w0[3];
          h1[r] += z4.x * w1[0] + z4.y * w1[1] + z4.z * w1[2] + z4.w * w1[3];
        }
      }
#pragma unroll
      for (int r = 0; r < 16; ++r) { h0[r] = gelu_f(h0[r]); h1[r] = gelu_f(h1[r]); }
    }
    LDS_FENCE();   // all z2 reads complete before overwrite

#pragma unroll
    for (int r = 0; r < 16; ++r) {
      f2ma v; v.x = h0[r]; v.y = h1[r];
      *(f2ma*)&zw[r * 132 + cb] = v;
    }
    LDS_FENCE();   // hidden visible

    // ---- P6: channel matmul2 (f32 VALU) + lane-local colsum ----
    float cc0, cc1;
    {
      float acc0[16], acc1[16];
      float b0 = cb2v[cb], b1 = cb2v[cb + 1];
#pragma unroll
      for (int r = 0; r < 16; ++r) { acc0[r] = b0; acc1[r] = b1; }
      for (int k = 0; k < 128; k += 4) {
        float w0[4], w1[4];
#pragma unroll
        for (int kk = 0; kk < 4; ++kk) {
          unsigned w = *(const u32ma*)&Wt2[(k + kk) * 128 + cb];
          unpack2(w, w0[kk], w1[kk]);
        }
#pragma unroll
        for (int r = 0; r < 16; ++r) {
          f4ma z4 = *(const f4ma*)&zw[r * 132 + k];
          acc0[r] += z4.x * w0[0] + z4.y * w0[1] + z4.z * w0[2] + z4.w * w0[3];
          acc1[r] += z4.x * w1[0] + z4.y * w1[1] + z4.z * w1[2] + z4.w * w1[3];
        }
      }
      cc0 = 0.f; cc1 = 0.f;
#pragma unroll
      for (int r = 0; r < 16; ++r) { cc0 += acc0[r]; cc1 += acc1[r]; }
    }

    // ---- P7: write output (all lane-local) ----
    {
      f2ma o;
      o.x = (cs0 + cc0) * (1.f / 16.f);
      o.y = (cs1 + cc1) * (1.f / 16.f);
      *(f2ma*)&out[((size_t)t * NN + node) * HH + cb] = o;
    }
    __builtin_amdgcn_sched_barrier(0);
  }
}

// ---------------- launch ----------------

extern "C" void kernel_launch(void* const* d_in, const int* in_sizes, int n_in,
                              void* d_out, int out_size, void* d_ws, size_t ws_size,
                              hipStream_t stream) {
  const int* node_t   = (const int*)d_in[0];
  const int* edges    = (const int*)d_in[1];
  const float* emb    = (const float*)d_in[3];
  const float* convW1 = (const float*)d_in[4];
  const float* convb1 = (const float*)d_in[5];
  const float* convW2 = (const float*)d_in[6];
  const float* convb2 = (const float*)d_in[7];
  const float* tn_g   = (const float*)d_in[8];
  const float* tn_b   = (const float*)d_in[9];
  const float* tok_w1 = (const float*)d_in[10];
  const float* tok_b1 = (const float*)d_in[11];
  const float* tok_w2 = (const float*)d_in[12];
  const float* tok_b2 = (const float*)d_in[13];
  const float* cn_g   = (const float*)d_in[14];
  const float* cn_b   = (const float*)d_in[15];
  const float* ch_w1  = (const float*)d_in[16];
  const float* ch_b1  = (const float*)d_in[17];
  const float* ch_w2  = (const float*)d_in[18];
  const float* ch_b2  = (const float*)d_in[19];
  float* out = (float*)d_out;

  char* ws = (char*)d_ws;
  size_t off = 0;
  auto alloc = [&](size_t bytes) -> void* {
    void* p = ws + off;
    off += (bytes + 511) & ~(size_t)511;
    return p;
  };
  float* xw1   = (float*)alloc((size_t)NN * HH * 4);
  float* hbufs = (float*)alloc((size_t)7 * NN * HH * 4);
  float* h     = (float*)alloc((size_t)NN * HH * 4);
  float* h2    = (float*)alloc((size_t)NN * HH * 4);
  float* dinv  = (float*)alloc((size_t)NN * 4);
  int*   cnt   = (int*)alloc((size_t)NN * 4);
  int*   cursor= (int*)alloc((size_t)NN * 4);
  int*   offs  = (int*)alloc((size_t)(NN + 1) * 4);
  int*   csrc  = (int*)alloc((size_t)EE * 4);
  float* cnorm = (float*)alloc((size_t)EE * 4);

  gemm128_kernel<<<512, 128, 0, stream>>>(emb, convW1, xw1, NN);

  for (int t = 0; t < 7; ++t) {
    const int* es = edges + (size_t)t * 2 * EE;
    const int* ed = es + EE;
    zero2_kernel<<<(NN + 255) / 256, 256, 0, stream>>>(cnt, cursor, NN);
    count_kernel<<<(EE + 255) / 256, 256, 0, stream>>>(ed, cnt, EE);
    dinv_kernel<<<(NN + 255) / 256, 256, 0, stream>>>(cnt, dinv, NN);
    scan_kernel<<<1, 1024, 0, stream>>>(cnt, offs, NN);
    fillcsr_kernel<<<(EE + 255) / 256, 256, 0, stream>>>(es, ed, offs, cursor, dinv,
                                                         csrc, cnorm, EE);
    agg_kernel<<<NN, 128, 0, stream>>>(xw1, csrc, cnorm, offs, dinv, convb1, 1, h);
    gemm128_kernel<<<512, 128, 0, stream>>>(h, convW2, h2, NN);
    agg_kernel<<<NN, 128, 0, stream>>>(h2, csrc, cnorm, offs, dinv, convb2, 0,
                                       hbufs + (size_t)t * NN * HH);
    mask_kernel<<<(KK * HH + 255) / 256, 256, 0, stream>>>(
        node_t + (size_t)t * KK, hbufs + (size_t)t * NN * HH, KK);
  }

  // One fused launch: items [0, 7*NN) = (t=1..7, node); item 7*NN = (t=0, node 0)
  mixer7_kernel<<<256, 512, 0, stream>>>(hbufs, tn_g, tn_b, tok_w1, tok_b1, tok_w2,
                                         tok_b2, cn_g, cn_b, ch_w1, ch_b1, ch_w2, ch_b2,
                                         out, 7 * NN + 1);
  bcast_kernel<<<((NN * HH - 128) + 255) / 256, 256, 0, stream>>>(out, NN * HH);
}

// Round 8
// 5733.290 us; speedup vs baseline: 1.0117x; 1.0117x over previous
//
#include <hip/hip_runtime.h>
#include <hip/hip_bf16.h>
#include <cstdint>
#include <cstddef>

#define NN 20000
#define HH 128
#define MM 16
#define KK 4000
#define EE 400000

typedef __attribute__((ext_vector_type(4), may_alias)) float f4ma;
typedef __attribute__((ext_vector_type(2), may_alias)) float f2ma;
typedef unsigned __attribute__((may_alias)) u32ma;
typedef float __attribute__((may_alias)) f32ma;

// Wave-local LDS ordering fence (completion wait + scheduler pin).
#define LDS_FENCE() do { \
    asm volatile("s_waitcnt lgkmcnt(0)" ::: "memory"); \
    __builtin_amdgcn_sched_barrier(0); \
  } while (0)

__device__ __forceinline__ float gelu_f(float x) {
  return 0.5f * x * (1.0f + erff(x * 0.70710678118654752440f));
}

__device__ __forceinline__ unsigned short f2bf(float f) {
  union { float f; unsigned u; } v; v.f = f;
  unsigned u = v.u;
  unsigned r = (u + 0x7FFFu + ((u >> 16) & 1u)) >> 16;  // RNE
  return (unsigned short)r;
}
__device__ __forceinline__ float bf2f(unsigned short s) {
  union { unsigned u; float f; } v; v.u = ((unsigned)s) << 16; return v.f;
}
__device__ __forceinline__ void unpack2(unsigned w, float& lo, float& hi) {
  lo = bf2f((unsigned short)(w & 0xFFFFu));
  hi = bf2f((unsigned short)(w >> 16));
}

// ---------------- GCN helper kernels (validated) ----------------

__global__ void zero2_kernel(int* __restrict__ a, int* __restrict__ b, int n) {
  int i = blockIdx.x * 256 + threadIdx.x;
  if (i < n) { a[i] = 0; b[i] = 0; }
}

__global__ void count_kernel(const int* __restrict__ dst, int* __restrict__ cnt, int n) {
  int e = blockIdx.x * 256 + threadIdx.x;
  if (e < n) atomicAdd(&cnt[dst[e]], 1);
}

__global__ void dinv_kernel(const int* __restrict__ cnt, float* __restrict__ dinv, int n) {
  int i = blockIdx.x * 256 + threadIdx.x;
  if (i < n) dinv[i] = rsqrtf((float)(cnt[i] + 1));
}

__global__ void scan_kernel(const int* __restrict__ cnt, int* __restrict__ offs, int n) {
  __shared__ int sh[1024];
  __shared__ int carry_s;
  int tid = threadIdx.x;
  if (tid == 0) carry_s = 0;
  __syncthreads();
  for (int base = 0; base < n; base += 1024) {
    int i = base + tid;
    int v = (i < n) ? cnt[i] : 0;
    sh[tid] = v;
    __syncthreads();
    for (int off = 1; off < 1024; off <<= 1) {
      int t = (tid >= off) ? sh[tid - off] : 0;
      __syncthreads();
      sh[tid] += t;
      __syncthreads();
    }
    int carry = carry_s;
    if (i < n) offs[i] = carry + sh[tid] - v;
    __syncthreads();
    if (tid == 1023) carry_s = carry + sh[1023];
    __syncthreads();
  }
  if (tid == 0) offs[n] = carry_s;
}

__global__ void fillcsr_kernel(const int* __restrict__ esrc, const int* __restrict__ edst,
                               const int* __restrict__ offs, int* __restrict__ cursor,
                               const float* __restrict__ dinv,
                               int* __restrict__ csrc, float* __restrict__ cnorm, int n) {
  int e = blockIdx.x * 256 + threadIdx.x;
  if (e < n) {
    int s = esrc[e], d = edst[e];
    int pos = offs[d] + atomicAdd(&cursor[d], 1);
    csrc[pos] = s;
    cnorm[pos] = dinv[s] * dinv[d];
  }
}

__global__ __launch_bounds__(128) void agg_kernel(const float* __restrict__ X,
    const int* __restrict__ csrc, const float* __restrict__ cnorm,
    const int* __restrict__ offs, const float* __restrict__ dinv,
    const float* __restrict__ bias, int relu, float* __restrict__ Y) {
  int i = blockIdx.x, c = threadIdx.x;
  float di = dinv[i];
  float acc = X[(size_t)i * HH + c] * di * di;
  int s = offs[i], e = offs[i + 1];
  for (int j = s; j < e; ++j) {
    acc += X[(size_t)csrc[j] * HH + c] * cnorm[j];
  }
  acc += bias[c];
  if (relu) acc = fmaxf(acc, 0.f);
  Y[(size_t)i * HH + c] = acc;
}

__global__ __launch_bounds__(128) void gemm128_kernel(const float* __restrict__ X,
    const float* __restrict__ W, float* __restrict__ Y, int nrows) {
  __shared__ float Ws[128 * 129];
  __shared__ float Xs[8 * 128];
  int tid = threadIdx.x;
  for (int idx = tid; idx < 16384; idx += 128) {
    int o = idx >> 7, k = idx & 127;
    Ws[o * 129 + k] = W[idx];
  }
  __syncthreads();
  for (int row0 = blockIdx.x * 8; row0 < nrows; row0 += gridDim.x * 8) {
    int nr = min(8, nrows - row0);
    for (int idx = tid; idx < nr * 128; idx += 128) Xs[idx] = X[(size_t)row0 * 128 + idx];
    __syncthreads();
    float acc[8] = {0, 0, 0, 0, 0, 0, 0, 0};
    for (int k = 0; k < 128; ++k) {
      float w = Ws[tid * 129 + k];
#pragma unroll
      for (int r = 0; r < 8; ++r) acc[r] += w * Xs[r * 128 + k];
    }
    for (int r = 0; r < nr; ++r) Y[(size_t)(row0 + r) * 128 + tid] = acc[r];
    __syncthreads();
  }
}

__global__ void mask_kernel(const int* __restrict__ nodes, float* __restrict__ H, int kn) {
  int idx = blockIdx.x * 256 + threadIdx.x;
  if (idx < kn * HH) {
    int j = idx >> 7, c = idx & 127;
    H[(size_t)nodes[j] * HH + c] = 0.f;
  }
}

__global__ void bcast_kernel(float* __restrict__ out, int total) {
  int idx = blockIdx.x * 256 + threadIdx.x + 128;
  if (idx < total) out[idx] = out[idx & 127];
}

// ---------------- mixer v8: v7 with the VGPR cap removed ----------------
// LDS (138.7 KB) already limits to 1 block/CU, so __launch_bounds__(512,1)
// raises the VGPR budget to 256 at IDENTICAL occupancy -> no spills.
// P3 z-arrays merged to scalars (-32 regs of peak pressure).

__global__ __launch_bounds__(512, 1) void mixer8_kernel(
    const float* __restrict__ hbufs,  // [7][NN][HH]
    const float* __restrict__ tn_g, const float* __restrict__ tn_b,
    const float* __restrict__ tok_w1, const float* __restrict__ tok_b1,
    const float* __restrict__ tok_w2, const float* __restrict__ tok_b2,
    const float* __restrict__ cn_g, const float* __restrict__ cn_b,
    const float* __restrict__ ch_w1, const float* __restrict__ ch_b1,
    const float* __restrict__ ch_w2, const float* __restrict__ ch_b2,
    float* __restrict__ out, int total_items) {
  __shared__ __align__(16) unsigned short Wt1[128 * 128];  // 32 KB, [k][o] bf16
  __shared__ __align__(16) unsigned short Wt2[128 * 128];  // 32 KB
  __shared__ __align__(16) float zf[8][16 * 132];          // 67.6 KB per-wave tiles
  __shared__ float tg[128], tbv[128], cg[128], cbv[128], cb1v[128], cb2v[128];
  __shared__ float tw1s[256], tw2s[256], tb1s[16], tb2s[16];

  const int tid = threadIdx.x;

  for (int idx = tid; idx < 16384; idx += 512) {
    int o = idx >> 7, k = idx & 127;
    Wt1[k * 128 + o] = f2bf(ch_w1[idx]);
    Wt2[k * 128 + o] = f2bf(ch_w2[idx]);
  }
  if (tid < 128) {
    tg[tid] = tn_g[tid]; tbv[tid] = tn_b[tid];
    cg[tid] = cn_g[tid]; cbv[tid] = cn_b[tid];
    cb1v[tid] = ch_b1[tid]; cb2v[tid] = ch_b2[tid];
  }
  if (tid < 256) { tw1s[tid] = tok_w1[tid]; tw2s[tid] = tok_w2[tid]; }
  if (tid < 16) { tb1s[tid] = tok_b1[tid]; tb2s[tid] = tok_b2[tid]; }
  __syncthreads();  // only block barrier

  const int wid = tid >> 6;
  const int lane = tid & 63;
  const int q = lane >> 4;
  const int h = lane & 15;
  f32ma* zw = (f32ma*)zf[wid];
  const int cb = q * 32 + 2 * h;

  const int gwave = blockIdx.x * 8 + wid;
  const int wstride = gridDim.x * 8;

  for (int item = gwave; item < total_items; item += wstride) {
    int t, node;
    if (item < 7 * NN) { t = item / NN + 1; node = item % NN; }
    else { t = 0; node = 0; }

    // ---- P1+P2: load row h, LN1 stats, write RAW x + (mu,rs) to tile ----
    {
      float xr[32];
      int src_t = h - (MM - t);
      if (src_t >= 0) {
        const float* hp = hbufs + ((size_t)src_t * NN + node) * HH + q * 32;
#pragma unroll
        for (int j = 0; j < 8; ++j) {
          f4ma v = *(const f4ma*)(hp + 4 * j);
          xr[4 * j] = v.x; xr[4 * j + 1] = v.y; xr[4 * j + 2] = v.z; xr[4 * j + 3] = v.w;
        }
      } else {
#pragma unroll
        for (int j = 0; j < 32; ++j) xr[j] = 0.f;
      }
      float s = 0.f, ss = 0.f;
#pragma unroll
      for (int j = 0; j < 32; ++j) { s += xr[j]; ss += xr[j] * xr[j]; }
      s += __shfl_xor(s, 16); ss += __shfl_xor(ss, 16);
      s += __shfl_xor(s, 32); ss += __shfl_xor(ss, 32);
      float mu = s * (1.f / 128.f);
      float var = fmaxf(ss * (1.f / 128.f) - mu * mu, 0.f);
      float rs = rsqrtf(var + 1e-5f);
#pragma unroll
      for (int m = 0; m < 8; ++m) {
        f4ma w;
        w.x = xr[4 * m]; w.y = xr[4 * m + 1]; w.z = xr[4 * m + 2]; w.w = xr[4 * m + 3];
        *(f4ma*)&zw[h * 132 + q * 32 + 4 * m] = w;
      }
      if (q == 0) {
        zw[h * 132 + 128] = mu;
        zw[h * 132 + 129] = rs;
      }
    }
    LDS_FENCE();   // x + (mu,rs) visible

    // ---- P3: column pass — LN1 on the fly, token-MLP, residual, colsum ----
    float cs0, cs1;
    {
      float xv0[16], xv1[16];
      float a0[16], a1[16];
      const float tg0 = tg[cb], tb0 = tbv[cb], tg1 = tg[cb + 1], tb1 = tbv[cb + 1];
#pragma unroll
      for (int hd = 0; hd < 16; ++hd) { a0[hd] = tb1s[hd]; a1[hd] = tb1s[hd]; }
#pragma unroll
      for (int r = 0; r < 16; ++r) {
        f2ma v = *(const f2ma*)&zw[r * 132 + cb];
        float mu = zw[r * 132 + 128];   // uniform addr -> broadcast
        float rs = zw[r * 132 + 129];
        xv0[r] = v.x; xv1[r] = v.y;
        float z0 = (v.x - mu) * rs * tg0 + tb0;
        float z1 = (v.y - mu) * rs * tg1 + tb1;
#pragma unroll
        for (int hd = 0; hd < 16; ++hd) {
          float w = tw1s[hd * 16 + r];
          a0[hd] += w * z0; a1[hd] += w * z1;
        }
      }
#pragma unroll
      for (int hd = 0; hd < 16; ++hd) { a0[hd] = gelu_f(a0[hd]); a1[hd] = gelu_f(a1[hd]); }
      cs0 = 0.f; cs1 = 0.f;
#pragma unroll
      for (int r = 0; r < 16; ++r) {
        float o0 = tb2s[r], o1 = tb2s[r];
#pragma unroll
        for (int hd = 0; hd < 16; ++hd) {
          float w = tw2s[r * 16 + hd];
          o0 += w * a0[hd]; o1 += w * a1[hd];
        }
        xv0[r] += o0; xv1[r] += o1;          // x_new
        cs0 += xv0[r]; cs1 += xv1[r];        // lane-local token-sum
        f2ma v; v.x = xv0[r]; v.y = xv1[r];
        *(f2ma*)&zw[r * 132 + cb] = v;
      }
    }
    LDS_FENCE();   // x_new visible

    // ---- P4: row pass — LN2 -> z2 ----
    {
      float xr[32];
#pragma unroll
      for (int j = 0; j < 8; ++j) {
        f4ma v = *(const f4ma*)&zw[h * 132 + q * 32 + 4 * j];
        xr[4 * j] = v.x; xr[4 * j + 1] = v.y; xr[4 * j + 2] = v.z; xr[4 * j + 3] = v.w;
      }
      float s = 0.f, ss = 0.f;
#pragma unroll
      for (int j = 0; j < 32; ++j) { s += xr[j]; ss += xr[j] * xr[j]; }
      s += __shfl_xor(s, 16); ss += __shfl_xor(ss, 16);
      s += __shfl_xor(s, 32); ss += __shfl_xor(ss, 32);
      float mu = s * (1.f / 128.f);
      float var = fmaxf(ss * (1.f / 128.f) - mu * mu, 0.f);
      float rs = rsqrtf(var + 1e-5f);
      LDS_FENCE();  // all column reads of x_new done before z2 overwrite
#pragma unroll
      for (int m = 0; m < 8; ++m) {
        f4ma w;
        int c = q * 32 + 4 * m;
        w.x = (xr[4 * m]     - mu) * rs * cg[c]     + cbv[c];
        w.y = (xr[4 * m + 1] - mu) * rs * cg[c + 1] + cbv[c + 1];
        w.z = (xr[4 * m + 2] - mu) * rs * cg[c + 2] + cbv[c + 2];
        w.w = (xr[4 * m + 3] - mu) * rs * cg[c + 3] + cbv[c + 3];
        *(f4ma*)&zw[h * 132 + c] = w;
      }
    }
    LDS_FENCE();   // z2 visible

    // ---- P5: channel matmul1 (f32 VALU): hidden = gelu(z2 @ W1^T + b1) ----
    float h0[16], h1[16];
    {
      float b0 = cb1v[cb], b1 = cb1v[cb + 1];
#pragma unroll
      for (int r = 0; r < 16; ++r) { h0[r] = b0; h1[r] = b1; }
      for (int k = 0; k < 128; k += 4) {
        float w0[4], w1[4];
#pragma unroll
        for (int kk = 0; kk < 4; ++kk) {
          unsigned w = *(const u32ma*)&Wt1[(k + kk) * 128 + cb];
          unpack2(w, w0[kk], w1[kk]);
        }
#pragma unroll
        for (int r = 0; r < 16; ++r) {
          f4ma z4 = *(const f4ma*)&zw[r * 132 + k];   // uniform addr -> broadcast
          h0[r] += z4.x * w0[0] + z4.y * w0[1] + z4.z * w0[2] + z4.w * w0[3];
          h1[r] += z4.x * w1[0] + z4.y * w1[1] + z4.z * w1[2] + z4.w * w1[3];
        }
      }
#pragma unroll
      for (int r = 0; r < 16; ++r) { h0[r] = gelu_f(h0[r]); h1[r] = gelu_f(h1[r]); }
    }
    LDS_FENCE();   // all z2 reads complete before overwrite

#pragma unroll
    for (int r = 0; r < 16; ++r) {
      f2ma v; v.x = h0[r]; v.y = h1[r];
      *(f2ma*)&zw[r * 132 + cb] = v;
    }
    LDS_FENCE();   // hidden visible

    // ---- P6: channel matmul2 (f32 VALU) + lane-local colsum ----
    float cc0, cc1;
    {
      float acc0[16], acc1[16];
      float b0 = cb2v[cb], b1 = cb2v[cb + 1];
#pragma unroll
      for (int r = 0; r < 16; ++r) { acc0[r] = b0; acc1[r] = b1; }
      for (int k = 0; k < 128; k += 4) {
        float w0[4], w1[4];
#pragma unroll
        for (int kk = 0; kk < 4; ++kk) {
          unsigned w = *(const u32ma*)&Wt2[(k + kk) * 128 + cb];
          unpack2(w, w0[kk], w1[kk]);
        }
#pragma unroll
        for (int r = 0; r < 16; ++r) {
          f4ma z4 = *(const f4ma*)&zw[r * 132 + k];
          acc0[r] += z4.x * w0[0] + z4.y * w0[1] + z4.z * w0[2] + z4.w * w0[3];
          acc1[r] += z4.x * w1[0] + z4.y * w1[1] + z4.z * w1[2] + z4.w * w1[3];
        }
      }
      cc0 = 0.f; cc1 = 0.f;
#pragma unroll
      for (int r = 0; r < 16; ++r) { cc0 += acc0[r]; cc1 += acc1[r]; }
    }

    // ---- P7: write output (all lane-local) ----
    {
      f2ma o;
      o.x = (cs0 + cc0) * (1.f / 16.f);
      o.y = (cs1 + cc1) * (1.f / 16.f);
      *(f2ma*)&out[((size_t)t * NN + node) * HH + cb] = o;
    }
    __builtin_amdgcn_sched_barrier(0);
  }
}

// ---------------- launch ----------------

extern "C" void kernel_launch(void* const* d_in, const int* in_sizes, int n_in,
                              void* d_out, int out_size, void* d_ws, size_t ws_size,
                              hipStream_t stream) {
  const int* node_t   = (const int*)d_in[0];
  const int* edges    = (const int*)d_in[1];
  const float* emb    = (const float*)d_in[3];
  const float* convW1 = (const float*)d_in[4];
  const float* convb1 = (const float*)d_in[5];
  const float* convW2 = (const float*)d_in[6];
  const float* convb2 = (const float*)d_in[7];
  const float* tn_g   = (const float*)d_in[8];
  const float* tn_b   = (const float*)d_in[9];
  const float* tok_w1 = (const float*)d_in[10];
  const float* tok_b1 = (const float*)d_in[11];
  const float* tok_w2 = (const float*)d_in[12];
  const float* tok_b2 = (const float*)d_in[13];
  const float* cn_g   = (const float*)d_in[14];
  const float* cn_b   = (const float*)d_in[15];
  const float* ch_w1  = (const float*)d_in[16];
  const float* ch_b1  = (const float*)d_in[17];
  const float* ch_w2  = (const float*)d_in[18];
  const float* ch_b2  = (const float*)d_in[19];
  float* out = (float*)d_out;

  char* ws = (char*)d_ws;
  size_t off = 0;
  auto alloc = [&](size_t bytes) -> void* {
    void* p = ws + off;
    off += (bytes + 511) & ~(size_t)511;
    return p;
  };
  float* xw1   = (float*)alloc((size_t)NN * HH * 4);
  float* hbufs = (float*)alloc((size_t)7 * NN * HH * 4);
  float* h     = (float*)alloc((size_t)NN * HH * 4);
  float* h2    = (float*)alloc((size_t)NN * HH * 4);
  float* dinv  = (float*)alloc((size_t)NN * 4);
  int*   cnt   = (int*)alloc((size_t)NN * 4);
  int*   cursor= (int*)alloc((size_t)NN * 4);
  int*   offs  = (int*)alloc((size_t)(NN + 1) * 4);
  int*   csrc  = (int*)alloc((size_t)EE * 4);
  float* cnorm = (float*)alloc((size_t)EE * 4);

  gemm128_kernel<<<512, 128, 0, stream>>>(emb, convW1, xw1, NN);

  for (int t = 0; t < 7; ++t) {
    const int* es = edges + (size_t)t * 2 * EE;
    const int* ed = es + EE;
    zero2_kernel<<<(NN + 255) / 256, 256, 0, stream>>>(cnt, cursor, NN);
    count_kernel<<<(EE + 255) / 256, 256, 0, stream>>>(ed, cnt, EE);
    dinv_kernel<<<(NN + 255) / 256, 256, 0, stream>>>(cnt, dinv, NN);
    scan_kernel<<<1, 1024, 0, stream>>>(cnt, offs, NN);
    fillcsr_kernel<<<(EE + 255) / 256, 256, 0, stream>>>(es, ed, offs, cursor, dinv,
                                                         csrc, cnorm, EE);
    agg_kernel<<<NN, 128, 0, stream>>>(xw1, csrc, cnorm, offs, dinv, convb1, 1, h);
    gemm128_kernel<<<512, 128, 0, stream>>>(h, convW2, h2, NN);
    agg_kernel<<<NN, 128, 0, stream>>>(h2, csrc, cnorm, offs, dinv, convb2, 0,
                                       hbufs + (size_t)t * NN * HH);
    mask_kernel<<<(KK * HH + 255) / 256, 256, 0, stream>>>(
        node_t + (size_t)t * KK, hbufs + (size_t)t * NN * HH, KK);
  }

  // One fused launch: items [0, 7*NN) = (t=1..7, node); item 7*NN = (t=0, node 0)
  mixer8_kernel<<<256, 512, 0, stream>>>(hbufs, tn_g, tn_b, tok_w1, tok_b1, tok_w2,
                                         tok_b2, cn_g, cn_b, ch_w1, ch_b1, ch_w2, ch_b2,
                                         out, 7 * NN + 1);
  bcast_kernel<<<((NN * HH - 128) + 255) / 256, 256, 0, stream>>>(out, NN * HH);
}